// Round 1
// baseline (4104.090 us; speedup 1.0000x reference)
//
#include <hip/hip_runtime.h>
#include <hip/hip_bf16.h>

namespace {

constexpr int NN   = 8192;    // nodes
constexpr int NE   = 131072;  // edges
constexpr int SD   = 256;     // SDIM
constexpr int ED   = 128;     // EDIM
constexpr int NL   = 5;       // layers
constexpr int DINc = 644;     // 2*SD + ED + 4
constexpr int KP1  = 672;     // DIN padded to mult of 32
constexpr int DOUTc= 513;
constexpr int HIDc = 256;

typedef __bf16 bf16x8 __attribute__((ext_vector_type(8)));
typedef float  f32x4  __attribute__((ext_vector_type(4)));

__device__ __forceinline__ float siluf(float x) { return x / (1.0f + __expf(-x)); }

enum { MODE_H = 0, MODE_OUT2 = 1, MODE_SADD = 2, MODE_SADD2 = 3 };
enum { SRC_FEAT = 0, SRC_BF16 = 1, SRC_F32 = 2 };

struct GemmArgs {
  const __hip_bfloat16* Wt;     // [256][K] bf16, row-major (k contiguous)
  const float* bias;            // raw f32 bias pointer (b1L / b2L / bU1L / bU2L)
  const __hip_bfloat16* Abf;    // SRC_BF16 source, [M][K]
  const float* Af32;            // SRC_F32 source, [M][K]
  const int* src; const int* tgt;
  const __hip_bfloat16* s_ln;   // [NN][256]
  const __hip_bfloat16* e_bf;   // [NE][128]
  const float* e_f32;           // layer0 e input
  const float* dv; const float* av; const float* pn;
  __hip_bfloat16* bf_out;       // h or t output
  float* wv_out;                // [NE][128]
  __hip_bfloat16* e_bf_out;     // [NE][128]
  float* e_f32_out;             // d_out e region
  float* s_out;                 // d_out s region (RMW)
  const int* rawcnt;
  int use_f32_e;
  int write_e_f32;
};

__device__ __forceinline__ uint4 cvt8f(const float* p) {
  alignas(16) __hip_bfloat16 t8[8];
#pragma unroll
  for (int i = 0; i < 8; i++) t8[i] = __float2bfloat16(p[i]);
  return *(const uint4*)t8;
}

template<int MODE, int SRC, int KTOT>
__global__ __launch_bounds__(256) void gemm_k(GemmArgs g) {
  constexpr int BM = 64, BK = 32, LST = BK + 8;  // stride 40 bf16 = 20 dw -> 2-way (free) conflicts
  __shared__ unsigned short Ash[BM][LST];
  __shared__ unsigned short Bsh[256][LST];
  const int tid  = threadIdx.x;
  const int lane = tid & 63;
  const int wave = tid >> 6;
  const int l16  = lane & 15, lhi = lane >> 4;
  const int row0 = blockIdx.x * BM;
  const int ar = tid >> 2, aq = tid & 3;   // staging: row ar (0..63), 8-bf16 quarter aq
  const int arow = row0 + ar;
  f32x4 acc[4][4] = {};
  int sn = 0, tn = 0;
  if constexpr (SRC == SRC_FEAT) { sn = g.src[arow]; tn = g.tgt[arow]; }

  for (int k0 = 0; k0 < KTOT; k0 += BK) {
    // ---- stage A (64 rows x 32 k)
    uint4 chunk;
    if constexpr (SRC == SRC_FEAT) {
      const int kq = k0 + aq * 8;
      if (k0 < 256) {
        chunk = *(const uint4*)(g.s_ln + sn * SD + kq);
      } else if (k0 < 512) {
        chunk = *(const uint4*)(g.s_ln + tn * SD + (kq - 256));
      } else if (k0 < 640) {
        const int off = kq - 512;
        if (g.use_f32_e) chunk = cvt8f(g.e_f32 + (size_t)arow * ED + off);
        else             chunk = *(const uint4*)(g.e_bf + (size_t)arow * ED + off);
      } else {
        alignas(16) __hip_bfloat16 t8[8];
#pragma unroll
        for (int i = 0; i < 8; i++) t8[i] = __float2bfloat16(0.0f);
        if (aq == 0) {
          t8[0] = __float2bfloat16(g.dv[arow]);
          t8[1] = __float2bfloat16(g.av[arow]);
          t8[2] = __float2bfloat16(g.pn[sn]);
          t8[3] = __float2bfloat16(g.pn[tn]);
        }
        chunk = *(const uint4*)t8;
      }
    } else if constexpr (SRC == SRC_BF16) {
      chunk = *(const uint4*)(g.Abf + (size_t)arow * KTOT + k0 + aq * 8);
    } else {
      chunk = cvt8f(g.Af32 + (size_t)arow * KTOT + k0 + aq * 8);
    }
    *(uint4*)&Ash[ar][aq * 8] = chunk;
    // ---- stage B (256 rows x 32 k)
#pragma unroll
    for (int i = 0; i < 4; i++) {
      const int c = tid + i * 256;
      const int n = c >> 2, q = c & 3;
      *(uint4*)&Bsh[n][q * 8] = *(const uint4*)(g.Wt + (size_t)n * KTOT + k0 + q * 8);
    }
    __syncthreads();
    bf16x8 afr[4], bfr[4];
#pragma unroll
    for (int fr = 0; fr < 4; fr++) afr[fr] = *(const bf16x8*)&Ash[fr * 16 + l16][lhi * 8];
#pragma unroll
    for (int fc = 0; fc < 4; fc++) bfr[fc] = *(const bf16x8*)&Bsh[wave * 64 + fc * 16 + l16][lhi * 8];
#pragma unroll
    for (int fr = 0; fr < 4; fr++)
#pragma unroll
      for (int fc = 0; fc < 4; fc++)
        acc[fr][fc] = __builtin_amdgcn_mfma_f32_16x16x32_bf16(afr[fr], bfr[fc], acc[fr][fc], 0, 0, 0);
    __syncthreads();
  }
  // ---- epilogue: D[row = 4*(lane>>4)+reg][col = lane&15] per 16x16 tile (HW-verified mapping)
#pragma unroll
  for (int fr = 0; fr < 4; fr++) {
#pragma unroll
    for (int fc = 0; fc < 4; fc++) {
      const int n = wave * 64 + fc * 16 + l16;
#pragma unroll
      for (int r = 0; r < 4; r++) {
        const int row = row0 + fr * 16 + lhi * 4 + r;
        const float valf = acc[fr][fc][r];
        if constexpr (MODE == MODE_H) {
          g.bf_out[(size_t)row * HIDc + n] = __float2bfloat16(siluf(valf + g.bias[n]));
        } else if constexpr (MODE == MODE_OUT2) {
          if (n < 128) {
            g.wv_out[(size_t)row * 128 + n] = valf + g.bias[256 + n];
          } else {
            const float sv = siluf(valf + g.bias[257 + n]);   // e_new cols = W2 cols 385..512
            g.e_bf_out[(size_t)row * ED + (n - 128)] = __float2bfloat16(sv);
            if (g.write_e_f32) g.e_f32_out[(size_t)row * ED + (n - 128)] = sv;
          }
        } else if constexpr (MODE == MODE_SADD) {
          const float rc = (float)g.rawcnt[row];
          g.s_out[(size_t)row * SD + n] += valf + rc * g.bias[n];
        } else {  // MODE_SADD2
          g.s_out[(size_t)row * SD + n] += valf + g.bias[n];
        }
      }
    }
  }
}

// ---- LayerNorm (+ node position norm). 4 nodes/block, wave per node.
__global__ __launch_bounds__(256) void ln_pn_k(const float* __restrict__ s, const float* __restrict__ p,
                                               const float* __restrict__ gl, const float* __restrict__ bl,
                                               __hip_bfloat16* __restrict__ s_ln, float* __restrict__ pn) {
  const int wave = threadIdx.x >> 6, lane = threadIdx.x & 63;
  const int node = blockIdx.x * 4 + wave;
  const float* srow = s + (size_t)node * SD;
  float x[4], sum = 0.f, sq = 0.f;
#pragma unroll
  for (int i = 0; i < 4; i++) { x[i] = srow[lane * 4 + i]; sum += x[i]; sq += x[i] * x[i]; }
#pragma unroll
  for (int off = 1; off < 64; off <<= 1) { sum += __shfl_xor(sum, off); sq += __shfl_xor(sq, off); }
  const float mu = sum * (1.0f / SD);
  const float var = sq * (1.0f / SD) - mu * mu;
  const float rstd = rsqrtf(var + 1e-5f);
#pragma unroll
  for (int i = 0; i < 4; i++) {
    const int c = lane * 4 + i;
    s_ln[(size_t)node * SD + c] = __float2bfloat16(gl[c] * (x[i] - mu) * rstd + bl[c]);
  }
  if (lane == 0) {
    const float p0 = p[node * 3], p1 = p[node * 3 + 1], p2 = p[node * 3 + 2];
    pn[node] = sqrtf(p0 * p0 + p1 * p1 + p2 * p2);
  }
}

__global__ void edge_attr_k(const float* __restrict__ p, const int* __restrict__ src, const int* __restrict__ tgt,
                            float* __restrict__ dv, float* __restrict__ av, float* __restrict__ rn) {
  const int e = blockIdx.x * blockDim.x + threadIdx.x;
  if (e >= NE) return;
  const int s_ = src[e], t_ = tgt[e];
  const float sx = p[s_ * 3], sy = p[s_ * 3 + 1], sz = p[s_ * 3 + 2];
  const float tx = p[t_ * 3], ty = p[t_ * 3 + 1], tz = p[t_ * 3 + 2];
  const float rx = tx - sx, ry = ty - sy, rz = tz - sz;
  const float a = tx * sx + ty * sy + tz * sz;
  const float rr = rx * rx + ry * ry + rz * rz;
  const float d = sqrtf(fmaxf(rr, 1e-6f));
  const float inv = 1.0f / (1.0f + d);
  dv[e] = d; av[e] = a;
  rn[e * 3] = rx * inv; rn[e * 3 + 1] = ry * inv; rn[e * 3 + 2] = rz * inv;
}

__global__ void count_k(const int* __restrict__ tgt, int* __restrict__ rawcnt) {
  const int e = blockIdx.x * blockDim.x + threadIdx.x;
  if (e < NE) atomicAdd(&rawcnt[tgt[e]], 1);
}

// ---- per-edge: Hagg += h ; wp = tanh(h.w384 + b) ; p/v message atomics. Wave per edge.
__global__ __launch_bounds__(256) void edge_msg_k(const __hip_bfloat16* __restrict__ h, const float* __restrict__ wv,
                                                  const __hip_bfloat16* __restrict__ w384, const float* __restrict__ b2L,
                                                  const float* __restrict__ vbuf, const float* __restrict__ rn,
                                                  const int* __restrict__ src, const int* __restrict__ tgt,
                                                  float* __restrict__ Hagg, float* __restrict__ vacc,
                                                  float* __restrict__ pacc, int hasv) {
  const int wave = threadIdx.x >> 6, lane = threadIdx.x & 63;
  const int e = blockIdx.x * 4 + wave;
  const int t_ = tgt[e], s_ = src[e];
  const __hip_bfloat16* hrow = h + (size_t)e * HIDc;
  uint2 hraw = *(const uint2*)(hrow + lane * 4);
  const __hip_bfloat16* hcp = (const __hip_bfloat16*)&hraw;
  float* HaggRow = Hagg + (size_t)t_ * HIDc;
  float wp = 0.f;
#pragma unroll
  for (int i = 0; i < 4; i++) {
    const float hv = __bfloat162float(hcp[i]);
    atomicAdd(&HaggRow[lane * 4 + i], hv);
    wp += hv * __bfloat162float(w384[lane * 4 + i]);
  }
#pragma unroll
  for (int off = 1; off < 64; off <<= 1) wp += __shfl_xor(wp, off);
  const float wpt = tanhf(wp + b2L[384]);
  if (lane < 3) atomicAdd(&pacc[t_ * 3 + lane], wpt * rn[e * 3 + lane]);
  const float wv1 = wv[(size_t)e * 128 + lane];
  const float wv2 = wv[(size_t)e * 128 + 64 + lane];
  const float* vsrc = vbuf + (size_t)s_ * 192;
  float* vrow = vacc + (size_t)t_ * 192;
#pragma unroll
  for (int c = 0; c < 3; c++) {
    float mv = wv2 * rn[e * 3 + c];
    if (hasv) mv += wv1 * vsrc[c * 64 + lane];
    atomicAdd(&vrow[c * 64 + lane], mv);
  }
}

__global__ __launch_bounds__(256) void node_upd_k(float* __restrict__ v, float* __restrict__ p,
                                                  const float* __restrict__ vacc, const float* __restrict__ pacc,
                                                  const int* __restrict__ rawcnt) {
  const int node = blockIdx.x, t = threadIdx.x;
  const float inv = 1.0f / fmaxf((float)rawcnt[node], 1.0f);
  if (t < 192)      v[(size_t)node * 192 + t] += vacc[(size_t)node * 192 + t] * inv;
  else if (t < 195) p[node * 3 + (t - 192)]   += pacc[node * 3 + (t - 192)] * inv;
}

__global__ void zero_k(float* __restrict__ ptr, int n) {
  const int i = blockIdx.x * blockDim.x + threadIdx.x;
  if (i < n) ptr[i] = 0.f;
}

// ---- weight prep: transpose to [l][n][k] bf16 (k contiguous)
__global__ void prep_w1t_k(const float* __restrict__ W1, __hip_bfloat16* __restrict__ W1T) {
  const int idx = blockIdx.x * blockDim.x + threadIdx.x;
  if (idx >= NL * HIDc * KP1) return;
  const int k = idx % KP1, n = (idx / KP1) % HIDc, l = idx / (KP1 * HIDc);
  const float v = (k < DINc) ? W1[((size_t)l * DINc + k) * HIDc + n] : 0.f;
  W1T[idx] = __float2bfloat16(v);
}

__global__ void prep_w2t_k(const float* __restrict__ W2, __hip_bfloat16* __restrict__ W2sT,
                           __hip_bfloat16* __restrict__ W2aT, __hip_bfloat16* __restrict__ w384) {
  const int idx = blockIdx.x * blockDim.x + threadIdx.x;
  if (idx >= NL * HIDc * HIDc) return;
  const int k = idx % HIDc, n = (idx / HIDc) % HIDc, l = idx / (HIDc * HIDc);
  const float* W2l = W2 + (size_t)l * HIDc * DOUTc;
  const int cs = (n < 128) ? (256 + n) : (257 + n);  // wv1|wv2 then e_new (skip col 384)
  W2sT[idx] = __float2bfloat16(W2l[(size_t)k * DOUTc + cs]);
  W2aT[idx] = __float2bfloat16(W2l[(size_t)k * DOUTc + n]);
  if (n == 0) w384[l * HIDc + k] = __float2bfloat16(W2l[(size_t)k * DOUTc + 384]);
}

__global__ void prep_ut_k(const float* __restrict__ U1, const float* __restrict__ U2,
                          __hip_bfloat16* __restrict__ U1T, __hip_bfloat16* __restrict__ U2T) {
  const int idx = blockIdx.x * blockDim.x + threadIdx.x;
  if (idx >= NL * HIDc * HIDc) return;
  const int k = idx % HIDc, n = (idx / HIDc) % HIDc, l = idx / (HIDc * HIDc);
  U1T[idx] = __float2bfloat16(U1[((size_t)l * HIDc + k) * HIDc + n]);
  U2T[idx] = __float2bfloat16(U2[((size_t)l * HIDc + k) * HIDc + n]);
}

}  // namespace

extern "C" void kernel_launch(void* const* d_in, const int* in_sizes, int n_in,
                              void* d_out, int out_size, void* d_ws, size_t ws_size,
                              hipStream_t stream) {
  (void)in_sizes; (void)n_in; (void)out_size; (void)ws_size;
  const float* s_in = (const float*)d_in[0];
  const float* v_in = (const float*)d_in[1];
  const float* p_in = (const float*)d_in[2];
  const float* e_in = (const float*)d_in[3];
  const int*   ei   = (const int*)d_in[4];
  const float* ln_g = (const float*)d_in[5];
  const float* ln_b = (const float*)d_in[6];
  const float* W1   = (const float*)d_in[7];
  const float* b1   = (const float*)d_in[8];
  const float* W2   = (const float*)d_in[9];
  const float* b2   = (const float*)d_in[10];
  const float* U1   = (const float*)d_in[11];
  const float* bU1  = (const float*)d_in[12];
  const float* U2   = (const float*)d_in[13];
  const float* bU2  = (const float*)d_in[14];

  float* s_o = (float*)d_out;
  float* v_o = s_o + (size_t)NN * SD;
  float* e_o = v_o + (size_t)NN * 192;
  float* p_o = e_o + (size_t)NE * ED;

  const int* srcp = ei;
  const int* tgtp = ei + NE;

  char* wp = (char*)d_ws;
  auto alloc = [&](size_t bytes) -> char* {
    char* r = wp; wp += (bytes + 255) & ~(size_t)255; return r;
  };
  __hip_bfloat16* s_ln = (__hip_bfloat16*)alloc((size_t)NN * SD * 2);
  __hip_bfloat16* hbuf = (__hip_bfloat16*)alloc((size_t)NE * HIDc * 2);
  __hip_bfloat16* ebf  = (__hip_bfloat16*)alloc((size_t)NE * ED * 2);
  __hip_bfloat16* tbuf = (__hip_bfloat16*)alloc((size_t)NN * HIDc * 2);
  float* wvbuf = (float*)alloc((size_t)NE * 128 * 4);
  float* dvbuf = (float*)alloc((size_t)NE * 4);
  float* avbuf = (float*)alloc((size_t)NE * 4);
  float* rnbuf = (float*)alloc((size_t)NE * 3 * 4);
  float* pnbuf = (float*)alloc((size_t)NN * 4);
  float* accs  = (float*)alloc((size_t)NN * 451 * 4);  // Hagg | vacc | pacc contiguous
  float* Hagg  = accs;
  float* vacc  = accs + (size_t)NN * SD;
  float* pacc  = vacc + (size_t)NN * 192;
  int*   rawcnt= (int*)alloc((size_t)NN * 4);
  __hip_bfloat16* W1T  = (__hip_bfloat16*)alloc((size_t)NL * HIDc * KP1 * 2);
  __hip_bfloat16* W2sT = (__hip_bfloat16*)alloc((size_t)NL * HIDc * HIDc * 2);
  __hip_bfloat16* W2aT = (__hip_bfloat16*)alloc((size_t)NL * HIDc * HIDc * 2);
  __hip_bfloat16* U1T  = (__hip_bfloat16*)alloc((size_t)NL * HIDc * HIDc * 2);
  __hip_bfloat16* U2T  = (__hip_bfloat16*)alloc((size_t)NL * HIDc * HIDc * 2);
  __hip_bfloat16* w384 = (__hip_bfloat16*)alloc((size_t)NL * HIDc * 2);

  hipMemcpyAsync(s_o, s_in, (size_t)NN * SD * 4, hipMemcpyDeviceToDevice, stream);
  hipMemcpyAsync(v_o, v_in, (size_t)NN * 192 * 4, hipMemcpyDeviceToDevice, stream);
  hipMemcpyAsync(p_o, p_in, (size_t)NN * 3 * 4, hipMemcpyDeviceToDevice, stream);

  prep_w1t_k<<<(NL * HIDc * KP1 + 255) / 256, 256, 0, stream>>>(W1, W1T);
  prep_w2t_k<<<(NL * HIDc * HIDc + 255) / 256, 256, 0, stream>>>(W2, W2sT, W2aT, w384);
  prep_ut_k<<<(NL * HIDc * HIDc + 255) / 256, 256, 0, stream>>>(U1, U2, U1T, U2T);
  zero_k<<<(NN + 255) / 256, 256, 0, stream>>>((float*)rawcnt, NN);
  count_k<<<NE / 256, 256, 0, stream>>>(tgtp, rawcnt);

  for (int l = 0; l < NL; l++) {
    zero_k<<<(NN * 451 + 255) / 256, 256, 0, stream>>>(accs, NN * 451);
    ln_pn_k<<<NN / 4, 256, 0, stream>>>(s_o, p_o, ln_g + l * SD, ln_b + l * SD, s_ln, pnbuf);
    edge_attr_k<<<NE / 256, 256, 0, stream>>>(p_o, srcp, tgtp, dvbuf, avbuf, rnbuf);

    GemmArgs g1{};
    g1.Wt = W1T + (size_t)l * HIDc * KP1; g1.bias = b1 + l * HIDc;
    g1.src = srcp; g1.tgt = tgtp; g1.s_ln = s_ln; g1.e_bf = ebf; g1.e_f32 = e_in;
    g1.dv = dvbuf; g1.av = avbuf; g1.pn = pnbuf; g1.bf_out = hbuf;
    g1.use_f32_e = (l == 0) ? 1 : 0;
    gemm_k<MODE_H, SRC_FEAT, KP1><<<NE / 64, 256, 0, stream>>>(g1);

    GemmArgs g2{};
    g2.Wt = W2sT + (size_t)l * HIDc * HIDc; g2.bias = b2 + l * DOUTc;
    g2.Abf = hbuf; g2.wv_out = wvbuf; g2.e_bf_out = ebf; g2.e_f32_out = e_o;
    g2.write_e_f32 = (l == NL - 1) ? 1 : 0;
    gemm_k<MODE_OUT2, SRC_BF16, HIDc><<<NE / 64, 256, 0, stream>>>(g2);

    edge_msg_k<<<NE / 4, 256, 0, stream>>>(hbuf, wvbuf, w384 + l * HIDc, b2 + l * DOUTc,
                                           v_o, rnbuf, srcp, tgtp, Hagg, vacc, pacc, (l > 0) ? 1 : 0);

    GemmArgs g3{};
    g3.Wt = W2aT + (size_t)l * HIDc * HIDc; g3.bias = b2 + l * DOUTc;
    g3.Af32 = Hagg; g3.s_out = s_o; g3.rawcnt = rawcnt;
    gemm_k<MODE_SADD, SRC_F32, HIDc><<<NN / 64, 256, 0, stream>>>(g3);

    node_upd_k<<<NN, 256, 0, stream>>>(v_o, p_o, vacc, pacc, rawcnt);

    if (l < NL - 1) {
      GemmArgs g4{};
      g4.Wt = U1T + (size_t)l * HIDc * HIDc; g4.bias = bU1 + l * HIDc;
      g4.Af32 = s_o; g4.bf_out = tbuf;
      gemm_k<MODE_H, SRC_F32, HIDc><<<NN / 64, 256, 0, stream>>>(g4);

      GemmArgs g5{};
      g5.Wt = U2T + (size_t)l * HIDc * HIDc; g5.bias = bU2 + l * HIDc;
      g5.Abf = tbuf; g5.s_out = s_o;
      gemm_k<MODE_SADD2, SRC_BF16, HIDc><<<NN / 64, 256, 0, stream>>>(g5);
    }
  }
}

// Round 2
// 1886.692 us; speedup vs baseline: 2.1753x; 2.1753x over previous
//
#include <hip/hip_runtime.h>
#include <hip/hip_bf16.h>

namespace {

constexpr int NN   = 8192;    // nodes
constexpr int NE   = 131072;  // edges
constexpr int SD   = 256;     // SDIM
constexpr int ED   = 128;     // EDIM
constexpr int NL   = 5;       // layers
constexpr int DINc = 644;     // 2*SD + ED + 4
constexpr int KP1  = 672;     // DIN padded to mult of 32
constexpr int DOUTc= 513;
constexpr int HIDc = 256;

typedef __bf16 bf16x8 __attribute__((ext_vector_type(8)));
typedef float  f32x4  __attribute__((ext_vector_type(4)));

__device__ __forceinline__ float siluf(float x) { return x / (1.0f + __expf(-x)); }

enum { MODE_H = 0, MODE_OUT2 = 1, MODE_SADD = 2, MODE_SADD2 = 3 };
enum { SRC_FEAT = 0, SRC_BF16 = 1, SRC_F32 = 2 };

struct GemmArgs {
  const __hip_bfloat16* Wt;     // [256][K] bf16, row-major (k contiguous)
  const float* bias;            // raw f32 bias pointer (b1L / b2L / bU1L / bU2L)
  const __hip_bfloat16* Abf;    // SRC_BF16 source, [M][K]
  const float* Af32;            // SRC_F32 source, [M][K]
  const int* src; const int* tgt;
  const __hip_bfloat16* s_ln;   // [NN][256]
  const __hip_bfloat16* e_bf;   // [NE][128]
  const float* e_f32;           // layer0 e input
  const float* dv; const float* av; const float* pn;
  __hip_bfloat16* bf_out;       // h or t output
  float* wv_out;                // [NE][128]
  __hip_bfloat16* e_bf_out;     // [NE][128]
  float* e_f32_out;             // d_out e region
  float* s_out;                 // d_out s region (RMW)
  const int* rawcnt;
  int use_f32_e;
  int write_e_f32;
};

__device__ __forceinline__ uint4 cvt8f(const float* p) {
  alignas(16) __hip_bfloat16 t8[8];
#pragma unroll
  for (int i = 0; i < 8; i++) t8[i] = __float2bfloat16(p[i]);
  return *(const uint4*)t8;
}

template<int MODE, int SRC, int KTOT>
__global__ __launch_bounds__(256) void gemm_k(GemmArgs g) {
  constexpr int BM = 64, BK = 32, LST = BK + 8;  // stride 40 bf16 = 20 dw -> 2-way (free) conflicts
  __shared__ unsigned short Ash[BM][LST];
  __shared__ unsigned short Bsh[256][LST];
  const int tid  = threadIdx.x;
  const int lane = tid & 63;
  const int wave = tid >> 6;
  const int l16  = lane & 15, lhi = lane >> 4;
  const int row0 = blockIdx.x * BM;
  const int ar = tid >> 2, aq = tid & 3;   // staging: row ar (0..63), 8-bf16 quarter aq
  const int arow = row0 + ar;
  f32x4 acc[4][4] = {};
  int sn = 0, tn = 0;
  if constexpr (SRC == SRC_FEAT) { sn = g.src[arow]; tn = g.tgt[arow]; }

  for (int k0 = 0; k0 < KTOT; k0 += BK) {
    // ---- stage A (64 rows x 32 k)
    uint4 chunk;
    if constexpr (SRC == SRC_FEAT) {
      const int kq = k0 + aq * 8;
      if (k0 < 256) {
        chunk = *(const uint4*)(g.s_ln + sn * SD + kq);
      } else if (k0 < 512) {
        chunk = *(const uint4*)(g.s_ln + tn * SD + (kq - 256));
      } else if (k0 < 640) {
        const int off = kq - 512;
        if (g.use_f32_e) chunk = cvt8f(g.e_f32 + (size_t)arow * ED + off);
        else             chunk = *(const uint4*)(g.e_bf + (size_t)arow * ED + off);
      } else {
        alignas(16) __hip_bfloat16 t8[8];
#pragma unroll
        for (int i = 0; i < 8; i++) t8[i] = __float2bfloat16(0.0f);
        if (aq == 0) {
          t8[0] = __float2bfloat16(g.dv[arow]);
          t8[1] = __float2bfloat16(g.av[arow]);
          t8[2] = __float2bfloat16(g.pn[sn]);
          t8[3] = __float2bfloat16(g.pn[tn]);
        }
        chunk = *(const uint4*)t8;
      }
    } else if constexpr (SRC == SRC_BF16) {
      chunk = *(const uint4*)(g.Abf + (size_t)arow * KTOT + k0 + aq * 8);
    } else {
      chunk = cvt8f(g.Af32 + (size_t)arow * KTOT + k0 + aq * 8);
    }
    *(uint4*)&Ash[ar][aq * 8] = chunk;
    // ---- stage B (256 rows x 32 k)
#pragma unroll
    for (int i = 0; i < 4; i++) {
      const int c = tid + i * 256;
      const int n = c >> 2, q = c & 3;
      *(uint4*)&Bsh[n][q * 8] = *(const uint4*)(g.Wt + (size_t)n * KTOT + k0 + q * 8);
    }
    __syncthreads();
    bf16x8 afr[4], bfr[4];
#pragma unroll
    for (int fr = 0; fr < 4; fr++) afr[fr] = *(const bf16x8*)&Ash[fr * 16 + l16][lhi * 8];
#pragma unroll
    for (int fc = 0; fc < 4; fc++) bfr[fc] = *(const bf16x8*)&Bsh[wave * 64 + fc * 16 + l16][lhi * 8];
#pragma unroll
    for (int fr = 0; fr < 4; fr++)
#pragma unroll
      for (int fc = 0; fc < 4; fc++)
        acc[fr][fc] = __builtin_amdgcn_mfma_f32_16x16x32_bf16(afr[fr], bfr[fc], acc[fr][fc], 0, 0, 0);
    __syncthreads();
  }
  // ---- epilogue: D[row = 4*(lane>>4)+reg][col = lane&15] per 16x16 tile (HW-verified mapping)
#pragma unroll
  for (int fr = 0; fr < 4; fr++) {
#pragma unroll
    for (int fc = 0; fc < 4; fc++) {
      const int n = wave * 64 + fc * 16 + l16;
#pragma unroll
      for (int r = 0; r < 4; r++) {
        const int row = row0 + fr * 16 + lhi * 4 + r;
        const float valf = acc[fr][fc][r];
        if constexpr (MODE == MODE_H) {
          g.bf_out[(size_t)row * HIDc + n] = __float2bfloat16(siluf(valf + g.bias[n]));
        } else if constexpr (MODE == MODE_OUT2) {
          if (n < 128) {
            g.wv_out[(size_t)row * 128 + n] = valf + g.bias[256 + n];
          } else {
            const float sv = siluf(valf + g.bias[257 + n]);   // e_new cols = W2 cols 385..512
            g.e_bf_out[(size_t)row * ED + (n - 128)] = __float2bfloat16(sv);
            if (g.write_e_f32) g.e_f32_out[(size_t)row * ED + (n - 128)] = sv;
          }
        } else if constexpr (MODE == MODE_SADD) {
          const float rc = (float)g.rawcnt[row];
          g.s_out[(size_t)row * SD + n] += valf + rc * g.bias[n];
        } else {  // MODE_SADD2
          g.s_out[(size_t)row * SD + n] += valf + g.bias[n];
        }
      }
    }
  }
}

// ---- LayerNorm (+ node position norm). 4 nodes/block, wave per node.
__global__ __launch_bounds__(256) void ln_pn_k(const float* __restrict__ s, const float* __restrict__ p,
                                               const float* __restrict__ gl, const float* __restrict__ bl,
                                               __hip_bfloat16* __restrict__ s_ln, float* __restrict__ pn) {
  const int wave = threadIdx.x >> 6, lane = threadIdx.x & 63;
  const int node = blockIdx.x * 4 + wave;
  const float* srow = s + (size_t)node * SD;
  float x[4], sum = 0.f, sq = 0.f;
#pragma unroll
  for (int i = 0; i < 4; i++) { x[i] = srow[lane * 4 + i]; sum += x[i]; sq += x[i] * x[i]; }
#pragma unroll
  for (int off = 1; off < 64; off <<= 1) { sum += __shfl_xor(sum, off); sq += __shfl_xor(sq, off); }
  const float mu = sum * (1.0f / SD);
  const float var = sq * (1.0f / SD) - mu * mu;
  const float rstd = rsqrtf(var + 1e-5f);
#pragma unroll
  for (int i = 0; i < 4; i++) {
    const int c = lane * 4 + i;
    s_ln[(size_t)node * SD + c] = __float2bfloat16(gl[c] * (x[i] - mu) * rstd + bl[c]);
  }
  if (lane == 0) {
    const float p0 = p[node * 3], p1 = p[node * 3 + 1], p2 = p[node * 3 + 2];
    pn[node] = sqrtf(p0 * p0 + p1 * p1 + p2 * p2);
  }
}

__global__ void edge_attr_k(const float* __restrict__ p, const int* __restrict__ src, const int* __restrict__ tgt,
                            float* __restrict__ dv, float* __restrict__ av, float* __restrict__ rn) {
  const int e = blockIdx.x * blockDim.x + threadIdx.x;
  if (e >= NE) return;
  const int s_ = src[e], t_ = tgt[e];
  const float sx = p[s_ * 3], sy = p[s_ * 3 + 1], sz = p[s_ * 3 + 2];
  const float tx = p[t_ * 3], ty = p[t_ * 3 + 1], tz = p[t_ * 3 + 2];
  const float rx = tx - sx, ry = ty - sy, rz = tz - sz;
  const float a = tx * sx + ty * sy + tz * sz;
  const float rr = rx * rx + ry * ry + rz * rz;
  const float d = sqrtf(fmaxf(rr, 1e-6f));
  const float inv = 1.0f / (1.0f + d);
  dv[e] = d; av[e] = a;
  rn[e * 3] = rx * inv; rn[e * 3 + 1] = ry * inv; rn[e * 3 + 2] = rz * inv;
}

__global__ void count_k(const int* __restrict__ tgt, int* __restrict__ rawcnt) {
  const int e = blockIdx.x * blockDim.x + threadIdx.x;
  if (e < NE) atomicAdd(&rawcnt[tgt[e]], 1);
}

// ---- exclusive scan of rawcnt[NN] -> off[NN+1]; single block of 256 threads, 32 elems each.
__global__ __launch_bounds__(256) void scan_k(const int* __restrict__ rawcnt, int* __restrict__ off) {
  __shared__ int ts[256];
  const int tid = threadIdx.x;
  const int base = tid * 32;
  int local[32];
  int s = 0;
#pragma unroll
  for (int i = 0; i < 32; i++) { local[i] = s; s += rawcnt[base + i]; }
  ts[tid] = s;
  __syncthreads();
  if (tid == 0) {
    int acc = 0;
    for (int i = 0; i < 256; i++) { int t = ts[i]; ts[i] = acc; acc += t; }
    off[NN] = acc;
  }
  __syncthreads();
  const int pre = ts[tid];
#pragma unroll
  for (int i = 0; i < 32; i++) off[base + i] = pre + local[i];
}

__global__ void scatter_k(const int* __restrict__ tgt, const int* __restrict__ off,
                          int* __restrict__ cursor, int* __restrict__ eperm) {
  const int e = blockIdx.x * blockDim.x + threadIdx.x;
  if (e < NE) {
    const int t = tgt[e];
    const int r = atomicAdd(&cursor[t], 1);
    eperm[off[t] + r] = e;
  }
}

// ---- per-edge wp: mp[e][c] = tanh(dot(h[e], w384) + b384) * rn[e][c]. Wave per edge.
__global__ __launch_bounds__(256) void wp_k(const __hip_bfloat16* __restrict__ h,
                                            const __hip_bfloat16* __restrict__ w384,
                                            const float* __restrict__ b2L,
                                            const float* __restrict__ rn,
                                            float* __restrict__ mp) {
  const int wave = threadIdx.x >> 6, lane = threadIdx.x & 63;
  const int e = blockIdx.x * 4 + wave;
  uint2 hraw = *(const uint2*)(h + (size_t)e * HIDc + lane * 4);
  uint2 wraw = *(const uint2*)(w384 + lane * 4);
  const __hip_bfloat16* hp = (const __hip_bfloat16*)&hraw;
  const __hip_bfloat16* wq = (const __hip_bfloat16*)&wraw;
  float s = 0.f;
#pragma unroll
  for (int i = 0; i < 4; i++) s += __bfloat162float(hp[i]) * __bfloat162float(wq[i]);
#pragma unroll
  for (int off = 1; off < 64; off <<= 1) s += __shfl_xor(s, off);
  if (lane < 3) {
    const float wpt = tanhf(s + b2L[384]);
    mp[(size_t)e * 3 + lane] = wpt * rn[(size_t)e * 3 + lane];
  }
}

// ---- CSR aggregation: one block (256 thr) per node. Sums h -> Hagg, v/p messages -> v_o/p_o.
// Reads vprev (pre-update v), writes v_o. Zero atomics.
__global__ __launch_bounds__(256) void agg_k(const int* __restrict__ off, const int* __restrict__ eperm,
                                             const int* __restrict__ srcp,
                                             const __hip_bfloat16* __restrict__ h,
                                             const float* __restrict__ wv,
                                             const float* __restrict__ mp,
                                             const float* __restrict__ rn,
                                             const float* __restrict__ vprev,
                                             float* __restrict__ Hagg,
                                             float* __restrict__ v_o, float* __restrict__ p_o,
                                             int hasv) {
  const int n = blockIdx.x;
  const int c = threadIdx.x;
  const int e0 = off[n], e1 = off[n + 1];
  const int c3 = c >> 6, ln = c & 63;
  float hs = 0.f, vs = 0.f, ps = 0.f;
  for (int j = e0; j < e1; j++) {
    const int e = eperm[j];
    hs += __bfloat162float(h[(size_t)e * HIDc + c]);
    if (c < 192) {
      float mv = wv[(size_t)e * 128 + 64 + ln] * rn[(size_t)e * 3 + c3];
      if (hasv) mv += wv[(size_t)e * 128 + ln] * vprev[(size_t)srcp[e] * 192 + c];
      vs += mv;
    } else if (c < 195) {
      ps += mp[(size_t)e * 3 + (c - 192)];
    }
  }
  Hagg[(size_t)n * HIDc + c] = hs;
  const float inv = 1.0f / fmaxf((float)(e1 - e0), 1.0f);
  if (c < 192)      v_o[(size_t)n * 192 + c] += vs * inv;
  else if (c < 195) p_o[n * 3 + (c - 192)]   += ps * inv;
}

__global__ void zero_k(float* __restrict__ ptr, int n) {
  const int i = blockIdx.x * blockDim.x + threadIdx.x;
  if (i < n) ptr[i] = 0.f;
}

// ---- weight prep: transpose to [l][n][k] bf16 (k contiguous)
__global__ void prep_w1t_k(const float* __restrict__ W1, __hip_bfloat16* __restrict__ W1T) {
  const int idx = blockIdx.x * blockDim.x + threadIdx.x;
  if (idx >= NL * HIDc * KP1) return;
  const int k = idx % KP1, n = (idx / KP1) % HIDc, l = idx / (KP1 * HIDc);
  const float v = (k < DINc) ? W1[((size_t)l * DINc + k) * HIDc + n] : 0.f;
  W1T[idx] = __float2bfloat16(v);
}

__global__ void prep_w2t_k(const float* __restrict__ W2, __hip_bfloat16* __restrict__ W2sT,
                           __hip_bfloat16* __restrict__ W2aT, __hip_bfloat16* __restrict__ w384) {
  const int idx = blockIdx.x * blockDim.x + threadIdx.x;
  if (idx >= NL * HIDc * HIDc) return;
  const int k = idx % HIDc, n = (idx / HIDc) % HIDc, l = idx / (HIDc * HIDc);
  const float* W2l = W2 + (size_t)l * HIDc * DOUTc;
  const int cs = (n < 128) ? (256 + n) : (257 + n);  // wv1|wv2 then e_new (skip col 384)
  W2sT[idx] = __float2bfloat16(W2l[(size_t)k * DOUTc + cs]);
  W2aT[idx] = __float2bfloat16(W2l[(size_t)k * DOUTc + n]);
  if (n == 0) w384[l * HIDc + k] = __float2bfloat16(W2l[(size_t)k * DOUTc + 384]);
}

__global__ void prep_ut_k(const float* __restrict__ U1, const float* __restrict__ U2,
                          __hip_bfloat16* __restrict__ U1T, __hip_bfloat16* __restrict__ U2T) {
  const int idx = blockIdx.x * blockDim.x + threadIdx.x;
  if (idx >= NL * HIDc * HIDc) return;
  const int k = idx % HIDc, n = (idx / HIDc) % HIDc, l = idx / (HIDc * HIDc);
  U1T[idx] = __float2bfloat16(U1[((size_t)l * HIDc + k) * HIDc + n]);
  U2T[idx] = __float2bfloat16(U2[((size_t)l * HIDc + k) * HIDc + n]);
}

}  // namespace

extern "C" void kernel_launch(void* const* d_in, const int* in_sizes, int n_in,
                              void* d_out, int out_size, void* d_ws, size_t ws_size,
                              hipStream_t stream) {
  (void)in_sizes; (void)n_in; (void)out_size; (void)ws_size;
  const float* s_in = (const float*)d_in[0];
  const float* v_in = (const float*)d_in[1];
  const float* p_in = (const float*)d_in[2];
  const float* e_in = (const float*)d_in[3];
  const int*   ei   = (const int*)d_in[4];
  const float* ln_g = (const float*)d_in[5];
  const float* ln_b = (const float*)d_in[6];
  const float* W1   = (const float*)d_in[7];
  const float* b1   = (const float*)d_in[8];
  const float* W2   = (const float*)d_in[9];
  const float* b2   = (const float*)d_in[10];
  const float* U1   = (const float*)d_in[11];
  const float* bU1  = (const float*)d_in[12];
  const float* U2   = (const float*)d_in[13];
  const float* bU2  = (const float*)d_in[14];

  float* s_o = (float*)d_out;
  float* v_o = s_o + (size_t)NN * SD;
  float* e_o = v_o + (size_t)NN * 192;
  float* p_o = e_o + (size_t)NE * ED;

  const int* srcp = ei;
  const int* tgtp = ei + NE;

  char* wp = (char*)d_ws;
  auto alloc = [&](size_t bytes) -> char* {
    char* r = wp; wp += (bytes + 255) & ~(size_t)255; return r;
  };
  __hip_bfloat16* s_ln = (__hip_bfloat16*)alloc((size_t)NN * SD * 2);
  __hip_bfloat16* hbuf = (__hip_bfloat16*)alloc((size_t)NE * HIDc * 2);
  __hip_bfloat16* ebf  = (__hip_bfloat16*)alloc((size_t)NE * ED * 2);
  __hip_bfloat16* tbuf = (__hip_bfloat16*)alloc((size_t)NN * HIDc * 2);
  float* wvbuf = (float*)alloc((size_t)NE * 128 * 4);
  float* dvbuf = (float*)alloc((size_t)NE * 4);
  float* avbuf = (float*)alloc((size_t)NE * 4);
  float* rnbuf = (float*)alloc((size_t)NE * 3 * 4);
  float* pnbuf = (float*)alloc((size_t)NN * 4);
  float* Hagg  = (float*)alloc((size_t)NN * SD * 4);
  float* vprev = (float*)alloc((size_t)NN * 192 * 4);
  float* mpbuf = (float*)alloc((size_t)NE * 3 * 4);
  int*   rawcnt= (int*)alloc((size_t)NN * 4);
  int*   offb  = (int*)alloc((size_t)(NN + 1) * 4);
  int*   cursor= (int*)alloc((size_t)NN * 4);
  int*   eperm = (int*)alloc((size_t)NE * 4);
  __hip_bfloat16* W1T  = (__hip_bfloat16*)alloc((size_t)NL * HIDc * KP1 * 2);
  __hip_bfloat16* W2sT = (__hip_bfloat16*)alloc((size_t)NL * HIDc * HIDc * 2);
  __hip_bfloat16* W2aT = (__hip_bfloat16*)alloc((size_t)NL * HIDc * HIDc * 2);
  __hip_bfloat16* U1T  = (__hip_bfloat16*)alloc((size_t)NL * HIDc * HIDc * 2);
  __hip_bfloat16* U2T  = (__hip_bfloat16*)alloc((size_t)NL * HIDc * HIDc * 2);
  __hip_bfloat16* w384 = (__hip_bfloat16*)alloc((size_t)NL * HIDc * 2);

  hipMemcpyAsync(s_o, s_in, (size_t)NN * SD * 4, hipMemcpyDeviceToDevice, stream);
  hipMemcpyAsync(v_o, v_in, (size_t)NN * 192 * 4, hipMemcpyDeviceToDevice, stream);
  hipMemcpyAsync(p_o, p_in, (size_t)NN * 3 * 4, hipMemcpyDeviceToDevice, stream);

  prep_w1t_k<<<(NL * HIDc * KP1 + 255) / 256, 256, 0, stream>>>(W1, W1T);
  prep_w2t_k<<<(NL * HIDc * HIDc + 255) / 256, 256, 0, stream>>>(W2, W2sT, W2aT, w384);
  prep_ut_k<<<(NL * HIDc * HIDc + 255) / 256, 256, 0, stream>>>(U1, U2, U1T, U2T);

  // ---- CSR build (once per call; edge_index is layer-invariant)
  zero_k<<<(2 * NN + 255) / 256, 256, 0, stream>>>((float*)rawcnt, 2 * NN);  // rawcnt + cursor (adjacent allocs... not adjacent; zero separately)
  zero_k<<<(NN + 255) / 256, 256, 0, stream>>>((float*)cursor, NN);
  count_k<<<NE / 256, 256, 0, stream>>>(tgtp, rawcnt);
  scan_k<<<1, 256, 0, stream>>>(rawcnt, offb);
  scatter_k<<<NE / 256, 256, 0, stream>>>(tgtp, offb, cursor, eperm);

  for (int l = 0; l < NL; l++) {
    ln_pn_k<<<NN / 4, 256, 0, stream>>>(s_o, p_o, ln_g + l * SD, ln_b + l * SD, s_ln, pnbuf);
    edge_attr_k<<<NE / 256, 256, 0, stream>>>(p_o, srcp, tgtp, dvbuf, avbuf, rnbuf);

    GemmArgs g1{};
    g1.Wt = W1T + (size_t)l * HIDc * KP1; g1.bias = b1 + l * HIDc;
    g1.src = srcp; g1.tgt = tgtp; g1.s_ln = s_ln; g1.e_bf = ebf; g1.e_f32 = e_in;
    g1.dv = dvbuf; g1.av = avbuf; g1.pn = pnbuf; g1.bf_out = hbuf;
    g1.use_f32_e = (l == 0) ? 1 : 0;
    gemm_k<MODE_H, SRC_FEAT, KP1><<<NE / 64, 256, 0, stream>>>(g1);

    GemmArgs g2{};
    g2.Wt = W2sT + (size_t)l * HIDc * HIDc; g2.bias = b2 + l * DOUTc;
    g2.Abf = hbuf; g2.wv_out = wvbuf; g2.e_bf_out = ebf; g2.e_f32_out = e_o;
    g2.write_e_f32 = (l == NL - 1) ? 1 : 0;
    gemm_k<MODE_OUT2, SRC_BF16, HIDc><<<NE / 64, 256, 0, stream>>>(g2);

    wp_k<<<NE / 4, 256, 0, stream>>>(hbuf, w384 + l * HIDc, b2 + l * DOUTc, rnbuf, mpbuf);

    // pre-update v snapshot (messages read v[src] from BEFORE this layer's update)
    hipMemcpyAsync(vprev, v_o, (size_t)NN * 192 * 4, hipMemcpyDeviceToDevice, stream);

    agg_k<<<NN, 256, 0, stream>>>(offb, eperm, srcp, hbuf, wvbuf, mpbuf, rnbuf, vprev,
                                  Hagg, v_o, p_o, (l > 0) ? 1 : 0);

    GemmArgs g3{};
    g3.Wt = W2aT + (size_t)l * HIDc * HIDc; g3.bias = b2 + l * DOUTc;
    g3.Af32 = Hagg; g3.s_out = s_o; g3.rawcnt = rawcnt;
    gemm_k<MODE_SADD, SRC_F32, HIDc><<<NN / 64, 256, 0, stream>>>(g3);

    if (l < NL - 1) {
      GemmArgs g4{};
      g4.Wt = U1T + (size_t)l * HIDc * HIDc; g4.bias = bU1 + l * HIDc;
      g4.Af32 = s_o; g4.bf_out = tbuf;
      gemm_k<MODE_H, SRC_F32, HIDc><<<NN / 64, 256, 0, stream>>>(g4);

      GemmArgs g5{};
      g5.Wt = U2T + (size_t)l * HIDc * HIDc; g5.bias = bU2 + l * HIDc;
      g5.Abf = tbuf; g5.s_out = s_o;
      gemm_k<MODE_SADD2, SRC_BF16, HIDc><<<NN / 64, 256, 0, stream>>>(g5);
    }
  }
}